// Round 12
// baseline (200.595 us; speedup 1.0000x reference)
//
#include <hip/hip_runtime.h>
#include <hip/hip_bf16.h>

typedef __hip_bfloat16 bf16;
typedef __attribute__((ext_vector_type(8))) short short8;
typedef __attribute__((ext_vector_type(4))) float f32x4;
typedef __attribute__((ext_vector_type(16))) float f32x16;

#define BB 4
#define CC 64
#define NN 4096           // 64*64
#define MH 512
#define MW 512
#define LS 72             // LDS row stride in bf16 elements

// ---- workspace layout (BYTE offsets; total ~4.67 MiB) ----
#define WB_AFC  ((size_t)0)         // f32[4*4096*64] att_fore UNNORMALIZED sums (atomic)
                                    // first 2 MB double as y1t (bf16 conv1 raw) before k_knorm
#define WB_DEN  ((size_t)4194304)   // f32[4*4096] softmax denominators (atomic)
#define WB_VIS  ((size_t)4259840)   // f32[4*4096] visatt (atomic)
#define WB_QIX  ((size_t)4325376)   // int[4*4096]
#define WB_KIX  ((size_t)4390912)   // int[4*4096]
#define WB_MFL  ((size_t)4456448)   // uchar[4*4096]
#define WB_CNT  ((size_t)4472832)   // int nq[4]; int nk[4]; uint vmaxbits (12 ints)
#define WB_STAT ((size_t)4472896)   // f32 gsum1[256]; gsq1[256]; gsum2[256]; gsq2[256]
#define WB_WT1  ((size_t)4476992)   // bf16[9*64*64] wT1
#define WB_WT2  ((size_t)4550720)   // bf16[9*64*64] wT2
#define WB_WFB  ((size_t)4624448)   // bf16 w1b[8192]; w2b[4096]; wfb[8192] (40960 B)

__device__ __forceinline__ float b2f(bf16 v) { return __bfloat162float(v); }
__device__ __forceinline__ float us2f(unsigned short u) { return __uint_as_float(((unsigned)u) << 16); }
__device__ __forceinline__ unsigned short f2bu(float f) {
  bf16 h = __float2bfloat16(f);
  return *(unsigned short*)&h;
}

// ------- 1. maxpool 8x8 on mask (4 lanes/window) + zero vis/stats/vmax -----
__global__ __launch_bounds__(256) void k_maxpool(const float* __restrict__ mask,
                                                 unsigned char* __restrict__ mfl,
                                                 float* __restrict__ vis,
                                                 float* __restrict__ gstat,
                                                 unsigned int* __restrict__ vmaxb) {
  int g = blockIdx.x * 256 + threadIdx.x;          // < 4*4096*4
  int o = g >> 2, sub = g & 3;
  int b = o >> 12, p = o & 4095;
  int py = p >> 6, px = p & 63;
  const float* mb = mask + (size_t)b * MH * MW + (py * 8 + sub * 2) * MW + px * 8;
  float mx = 0.f;
  #pragma unroll
  for (int dy = 0; dy < 2; ++dy) {
    const float4* r4 = (const float4*)(mb + dy * MW);
    float4 a = r4[0], c = r4[1];
    mx = fmaxf(mx, fmaxf(fmaxf(a.x, a.y), fmaxf(a.z, a.w)));
    mx = fmaxf(mx, fmaxf(fmaxf(c.x, c.y), fmaxf(c.z, c.w)));
  }
  mx = fmaxf(mx, __shfl_xor(mx, 1));
  mx = fmaxf(mx, __shfl_xor(mx, 2));
  if (sub == 0) {
    mfl[o] = (mx > 0.f) ? 1 : 0;
    vis[o] = 0.f;
  }
  if (g < 1024) gstat[g] = 0.f;
  if (g == 0) vmaxb[0] = 0u;
}

// ---------------- 2. fg/bg index compaction (1 wave per batch) -------------
__global__ __launch_bounds__(64) void k_compact(const unsigned char* __restrict__ mfl,
                                                int* __restrict__ qidx, int* __restrict__ kidx,
                                                int* __restrict__ nq, int* __restrict__ nk) {
  int b = blockIdx.x, lane = threadIdx.x;
  int qb = 0, kb = 0;
  for (int it = 0; it < 64; ++it) {
    int p = it * 64 + lane;
    bool f = mfl[b * NN + p] != 0;
    unsigned long long bal = __ballot(f);
    int before = __popcll(bal & ((1ULL << lane) - 1ULL));
    if (f)  qidx[b * NN + qb + before] = p;
    if (!f) kidx[b * NN + kb + (lane - before)] = p;
    int cnt = __popcll(bal);
    qb += cnt; kb += 64 - cnt;
  }
  if (lane == 0) { nq[b] = qb; nk[b] = kb; }
}

// -------- 3. transpose x -> bf16 pixel-major (xt) --------------------------
__global__ __launch_bounds__(256) void k_xT(const float* __restrict__ x,
                                            unsigned short* __restrict__ xt) {
  int b = blockIdx.x >> 6, p0 = (blockIdx.x & 63) * 64;
  __shared__ float lx[64][65];
  int t = threadIdx.x;
  const float* xb = x + (size_t)b * CC * NN + p0;
  for (int idx = t; idx < 4096; idx += 256) {
    int c = idx >> 6, j = idx & 63;
    lx[j][c] = xb[c * NN + j];
  }
  __syncthreads();
  unsigned short* xo = xt + ((size_t)b * NN + p0) * 64;
  for (int idx = t; idx < 2048; idx += 256) {
    int j = idx >> 5, c2 = (idx & 31) * 2;
    ushort2 w2;
    w2.x = f2bu(lx[j][c2]);
    w2.y = f2bu(lx[j][c2 + 1]);
    *(ushort2*)&xo[j * 64 + c2] = w2;
  }
}

// -------- 4. weight prep: conv wT + fusion weights -> bf16 -----------------
__global__ __launch_bounds__(256) void k_wprep(const float* __restrict__ w1,
                                               const float* __restrict__ w2,
                                               const float* __restrict__ fw1,
                                               const float* __restrict__ fw2,
                                               const float* __restrict__ fwf,
                                               unsigned short* __restrict__ wT1,
                                               unsigned short* __restrict__ wT2,
                                               unsigned short* __restrict__ wfb) {
  int i = blockIdx.x * 256 + threadIdx.x;   // < 57344
  if (i < 36864) {
    int tap = i >> 12;
    int rem = i & 4095;
    int co = rem >> 6, ci = rem & 63;
    int src = (co * 64 + ci) * 9 + tap;
    wT1[i] = f2bu(w1[src]);
    wT2[i] = f2bu(w2[src]);
  } else if (i < 57344) {
    int j = i - 36864;
    if (j < 8192)       wfb[j] = f2bu(fw1[j]);                 // w1b
    else if (j < 12288) wfb[j] = f2bu(fw2[j - 8192]);          // w2b
    else                wfb[j] = f2bu(fwf[j - 12288]);         // wfb
  }
}

// -------- 5. MFMA conv3x3(pad1) as 9 row-gathered GEMMs --------------------
template <bool NORM_IN>
__global__ __launch_bounds__(256) void k_convm(const unsigned short* __restrict__ src,
                                               const unsigned short* __restrict__ wT,
                                               const float* __restrict__ insum,
                                               const float* __restrict__ insq,
                                               unsigned short* __restrict__ dst,
                                               float* __restrict__ gsum,
                                               float* __restrict__ gsq) {
  int b = blockIdx.y;
  int r = blockIdx.x;              // image row 0..63
  __shared__ unsigned short bx[198 * LS];   // 28.5 KB
  __shared__ float nmean[64], ninv[64];
  int t = threadIdx.x;
  if (NORM_IN) {
    if (t < 64) {
      float m = insum[b * 64 + t] * (1.f / NN);
      float v = fmaxf(insq[b * 64 + t] * (1.f / NN) - m * m, 0.f);
      nmean[t] = m; ninv[t] = rsqrtf(v + 1e-5f);
    }
    __syncthreads();
  }
  const unsigned short* sb = src + (size_t)b * NN * 64;
  for (int idx = t; idx < 198 * 8; idx += 256) {
    int row = idx >> 3, c8 = (idx & 7) * 8;
    int dy = row / 66;
    int cx = row - dy * 66 - 1;
    int rr = r + dy - 1;
    uint4 v = make_uint4(0u, 0u, 0u, 0u);
    if ((unsigned)rr < 64u && (unsigned)cx < 64u) {
      v = *(const uint4*)(sb + ((size_t)(rr * 64 + cx)) * 64 + c8);
      if (NORM_IN) {
        unsigned short* e = (unsigned short*)&v;
        #pragma unroll
        for (int j = 0; j < 8; ++j)
          e[j] = f2bu(fmaxf((us2f(e[j]) - nmean[c8 + j]) * ninv[c8 + j], 0.f));
      }
    }
    *(uint4*)&bx[row * LS + c8] = v;
  }
  __syncthreads();
  int lane = t & 63;
  int quad = lane >> 4, col = lane & 15;
  int qw = (t >> 6) * 16;          // co strip
  f32x4 acc[4] = {{0.f,0.f,0.f,0.f},{0.f,0.f,0.f,0.f},{0.f,0.f,0.f,0.f},{0.f,0.f,0.f,0.f}};
  #pragma unroll
  for (int tap = 0; tap < 9; ++tap) {
    int dy = tap / 3, dx = tap - dy * 3 - 1;
    const unsigned short* wrow = wT + ((size_t)tap * 64 + qw + col) * 64;
    short8 a0 = *(const short8*)(wrow + quad * 8);
    short8 a1 = *(const short8*)(wrow + 32 + quad * 8);
    int rbase = dy * 66 + dx + 1;
    #pragma unroll
    for (int nt = 0; nt < 4; ++nt) {
      int row = rbase + nt * 16 + col;
      short8 b0 = *(const short8*)&bx[row * LS + quad * 8];
      short8 b1 = *(const short8*)&bx[row * LS + 32 + quad * 8];
      acc[nt] = __builtin_amdgcn_mfma_f32_16x16x32_bf16(a0, b0, acc[nt], 0, 0, 0);
      acc[nt] = __builtin_amdgcn_mfma_f32_16x16x32_bf16(a1, b1, acc[nt], 0, 0, 0);
    }
  }
  #pragma unroll
  for (int rr = 0; rr < 4; ++rr) {
    float s1 = acc[0][rr] + acc[1][rr] + acc[2][rr] + acc[3][rr];
    float s2 = acc[0][rr]*acc[0][rr] + acc[1][rr]*acc[1][rr]
             + acc[2][rr]*acc[2][rr] + acc[3][rr]*acc[3][rr];
    s1 += __shfl_xor(s1, 1); s2 += __shfl_xor(s2, 1);
    s1 += __shfl_xor(s1, 2); s2 += __shfl_xor(s2, 2);
    s1 += __shfl_xor(s1, 4); s2 += __shfl_xor(s2, 4);
    s1 += __shfl_xor(s1, 8); s2 += __shfl_xor(s2, 8);
    if (col == 0) {
      int co = qw + quad * 4 + rr;
      atomicAdd(&gsum[b * 64 + co], s1);
      atomicAdd(&gsq[b * 64 + co], s2);
    }
  }
  __syncthreads();
  #pragma unroll
  for (int nt = 0; nt < 4; ++nt)
    #pragma unroll
    for (int rr = 0; rr < 4; ++rr)
      bx[(nt * 16 + col) * LS + qw + quad * 4 + rr] = f2bu(acc[nt][rr]);
  __syncthreads();
  unsigned short* db = dst + ((size_t)b * NN + r * 64) * 64;
  for (int idx = t; idx < 512; idx += 256) {
    int px = idx >> 3, c8 = (idx & 7) * 8;
    *(uint4*)(db + (size_t)px * 64 + c8) = *(const uint4*)&bx[px * LS + c8];
  }
}

// -------- 6. fused inorm2 + residual + relu + L2-norm; zero afc/den --------
__global__ __launch_bounds__(256) void k_knorm(unsigned short* __restrict__ kxt,
                                               const unsigned short* __restrict__ xt,
                                               const float* __restrict__ gsum,
                                               const float* __restrict__ gsq,
                                               float* __restrict__ afc,
                                               float* __restrict__ den) {
  int b = blockIdx.x >> 6;
  int p0 = (blockIdx.x & 63) * 64;
  __shared__ float m2[64], i2[64];
  int t = threadIdx.x;
  if (t < 64) {
    float m = gsum[b * 64 + t] * (1.f / NN);
    float v = fmaxf(gsq[b * 64 + t] * (1.f / NN) - m * m, 0.f);
    m2[t] = m; i2[t] = rsqrtf(v + 1e-5f);
  }
  size_t gid = (size_t)blockIdx.x * 256 + t;
  float4 z4 = make_float4(0.f, 0.f, 0.f, 0.f);
  float4* az = (float4*)afc;
  #pragma unroll
  for (int j = 0; j < 4; ++j) az[gid + (size_t)j * 65536] = z4;
  if (gid < 16384) den[gid] = 0.f;
  __syncthreads();
  int px = t >> 2, c0 = (t & 3) * 16;
  size_t base = ((size_t)b * NN + p0 + px) * 64 + c0;
  unsigned short kv[16], xv[16];
  *(uint4*)&kv[0] = *(const uint4*)(kxt + base);
  *(uint4*)&kv[8] = *(const uint4*)(kxt + base + 8);
  *(uint4*)&xv[0] = *(const uint4*)(xt + base);
  *(uint4*)&xv[8] = *(const uint4*)(xt + base + 8);
  float v[16]; float ss = 0.f;
  #pragma unroll
  for (int j = 0; j < 16; ++j) {
    float f = fmaxf((us2f(kv[j]) - m2[c0 + j]) * i2[c0 + j] + us2f(xv[j]), 0.f);
    v[j] = f; ss += f * f;
  }
  ss += __shfl_xor(ss, 1);
  ss += __shfl_xor(ss, 2);
  float inv = 1.f / (sqrtf(ss) + 1e-8f);
  #pragma unroll
  for (int j = 0; j < 16; ++j) kv[j] = f2bu(v[j] * inv);
  *(uint4*)(kxt + base) = *(const uint4*)&kv[0];
  *(uint4*)(kxt + base + 8) = *(const uint4*)&kv[8];
}

// -------- 7. attention pass 1: 32x32 MFMA, K-split x4, atomic combine ------
// wave = one 32x32 quadrant: QK (qh,kh); PV (qh,ch=kh).
__global__ __launch_bounds__(256) void k_att1(const unsigned short* __restrict__ khat,
                                              const unsigned short* __restrict__ xt,
                                              const int* __restrict__ qidx, const int* __restrict__ kidx,
                                              const int* __restrict__ nqv, const int* __restrict__ nkv,
                                              float* __restrict__ afc, float* __restrict__ den) {
  int b = blockIdx.y;
  int nqb = nqv[b], nkb = nkv[b];
  int q0 = (blockIdx.x >> 2) * 64;
  int part = blockIdx.x & 3;
  if (q0 >= nqb) return;
  int kbeg = (part * nkb) >> 2;
  int kend = ((part + 1) * nkb) >> 2;
  __shared__ unsigned short lq [64 * LS];   // Q   [q][c]
  __shared__ unsigned short lk [64 * LS];   // K   [k][c]
  __shared__ unsigned short lvT[64 * LS];   // V^T [c][k-swizzled]
  __shared__ unsigned short le [64 * LS];   // E   [q][k]
  int t = threadIdx.x;
  int wave = t >> 6, lane = t & 63;
  int l31 = lane & 31, lhi = lane >> 5;
  int qh = wave >> 1, kh = wave & 1;
  const int* qix = qidx + b * NN;
  const int* kix = kidx + b * NN;
  const unsigned short* khb = khat + (size_t)b * NN * 64;
  const unsigned short* xtb = xt + (size_t)b * NN * 64;
  for (int idx = t; idx < 512; idx += 256) {
    int q = idx >> 3, c8 = (idx & 7) * 8;
    uint4 v = make_uint4(0u, 0u, 0u, 0u);
    if (q0 + q < nqb) v = *(const uint4*)(khb + (size_t)qix[q0 + q] * 64 + c8);
    *(uint4*)&lq[q * LS + c8] = v;
  }
  f32x16 pv, dsum;
  #pragma unroll
  for (int i = 0; i < 16; ++i) { pv[i] = 0.f; dsum[i] = 0.f; }
  // staging decomposition for V^T pairs
  int kp2 = t >> 3, vc8 = (t & 7) * 8, vcc = (t & 7);
  for (int j0 = kbeg; j0 < kend; j0 += 64) {
    __syncthreads();
    for (int idx = t; idx < 512; idx += 256) {
      int k = idx >> 3, c8 = (idx & 7) * 8;
      uint4 v = make_uint4(0u, 0u, 0u, 0u);
      if (j0 + k < kend) v = *(const uint4*)(khb + (size_t)kix[j0 + k] * 64 + c8);
      *(uint4*)&lk[k * LS + c8] = v;
    }
    {
      uint4 v0 = make_uint4(0u, 0u, 0u, 0u);
      uint4 v1 = make_uint4(0u, 0u, 0u, 0u);
      int ka = j0 + 2 * kp2, kb2 = ka + 1;
      if (ka  < kend) v0 = *(const uint4*)(xtb + (size_t)kix[ka]  * 64 + vc8);
      if (kb2 < kend) v1 = *(const uint4*)(xtb + (size_t)kix[kb2] * 64 + vc8);
      const unsigned short* e0 = (const unsigned short*)&v0;
      const unsigned short* e1 = (const unsigned short*)&v1;
      int pbase = kp2 & 3, prun = kp2 >> 2;
      int pp = pbase + (((prun) ^ vcc) << 2);
      #pragma unroll
      for (int jj = 0; jj < 8; ++jj) {
        int c = vc8 + jj;
        unsigned int w2 = (unsigned)e0[jj] | ((unsigned)e1[jj] << 16);
        *(unsigned int*)&lvT[c * LS + pp * 2] = w2;
      }
    }
    __syncthreads();
    // QK: quadrant (qh, kh), K-dim = 64 channels in 4 MFMA steps
    f32x16 s;
    #pragma unroll
    for (int i = 0; i < 16; ++i) s[i] = 0.f;
    #pragma unroll
    for (int ks = 0; ks < 4; ++ks) {
      short8 a  = *(const short8*)&lq[(qh * 32 + l31) * LS + ks * 16 + lhi * 8];
      short8 bk = *(const short8*)&lk[(kh * 32 + l31) * LS + ks * 16 + lhi * 8];
      s = __builtin_amdgcn_mfma_f32_32x32x16_bf16(a, bk, s, 0, 0, 0);
    }
    bool kval = (j0 + kh * 32 + l31) < kend;
    #pragma unroll
    for (int reg = 0; reg < 16; ++reg) {
      float e = kval ? __expf(20.f * s[reg]) : 0.f;
      dsum[reg] += e;
      int row = (reg & 3) + 8 * (reg >> 2) + 4 * lhi;
      le[(qh * 32 + row) * LS + kh * 32 + l31] = f2bu(e);
    }
    __syncthreads();
    // PV: quadrant (qh, ch=kh), K-dim = 64 keys in 4 MFMA steps
    int c = kh * 32 + l31;
    int c37 = (c >> 3) & 7;
    #pragma unroll
    for (int ks = 0; ks < 4; ++ks) {
      short8 a  = *(const short8*)&le[(qh * 32 + l31) * LS + ks * 16 + lhi * 8];
      int run = ks * 2 + lhi;
      short8 bv = *(const short8*)&lvT[c * LS + ((run ^ c37) << 3)];
      pv = __builtin_amdgcn_mfma_f32_32x32x16_bf16(a, bv, pv, 0, 0, 0);
    }
  }
  #pragma unroll
  for (int reg = 0; reg < 16; ++reg) {
    float v = dsum[reg];
    v += __shfl_xor(v, 1); v += __shfl_xor(v, 2); v += __shfl_xor(v, 4);
    v += __shfl_xor(v, 8); v += __shfl_xor(v, 16);
    int row = (reg & 3) + 8 * (reg >> 2) + 4 * lhi;
    int qq = q0 + qh * 32 + row;
    if (l31 == 0 && qq < nqb) atomicAdd(&den[b * NN + qq], v);
  }
  #pragma unroll
  for (int reg = 0; reg < 16; ++reg) {
    int row = (reg & 3) + 8 * (reg >> 2) + 4 * lhi;
    int qq = q0 + qh * 32 + row;
    if (qq < nqb) atomicAdd(&afc[((size_t)b * NN + qq) * 64 + kh * 32 + l31], pv[reg]);
  }
}

// -------- 8. attention pass 2: 32x32 MFMA, Q-split x4, atomic vis ----------
__global__ __launch_bounds__(256) void k_att2(const unsigned short* __restrict__ khat,
                                              const int* __restrict__ qidx, const int* __restrict__ kidx,
                                              const int* __restrict__ nqv, const int* __restrict__ nkv,
                                              const float* __restrict__ den, float* __restrict__ vis) {
  int b = blockIdx.y;
  int nqb = nqv[b], nkb = nkv[b];
  int k0 = (blockIdx.x >> 2) * 64;
  int part = blockIdx.x & 3;
  if (k0 >= nkb) return;
  int qbeg = (part * nqb) >> 2;
  int qend = ((part + 1) * nqb) >> 2;
  __shared__ unsigned short lk[64 * LS];
  __shared__ unsigned short lq[64 * LS];
  __shared__ float w[64];
  int t = threadIdx.x;
  int wave = t >> 6, lane = t & 63;
  int l31 = lane & 31, lhi = lane >> 5;
  int kh = wave >> 1, qh = wave & 1;
  const int* qix = qidx + b * NN;
  const int* kix = kidx + b * NN;
  const unsigned short* khb = khat + (size_t)b * NN * 64;
  for (int idx = t; idx < 512; idx += 256) {
    int k = idx >> 3, c8 = (idx & 7) * 8;
    uint4 v = make_uint4(0u, 0u, 0u, 0u);
    if (k0 + k < nkb) v = *(const uint4*)(khb + (size_t)kix[k0 + k] * 64 + c8);
    *(uint4*)&lk[k * LS + c8] = v;
  }
  f32x16 vacc;
  #pragma unroll
  for (int i = 0; i < 16; ++i) vacc[i] = 0.f;
  for (int i0 = qbeg; i0 < qend; i0 += 64) {
    __syncthreads();
    for (int idx = t; idx < 512; idx += 256) {
      int q = idx >> 3, c8 = (idx & 7) * 8;
      uint4 v = make_uint4(0u, 0u, 0u, 0u);
      if (i0 + q < qend) v = *(const uint4*)(khb + (size_t)qix[i0 + q] * 64 + c8);
      *(uint4*)&lq[q * LS + c8] = v;
    }
    if (t < 64) {
      int qq = i0 + t;
      float d = (qq < qend) ? den[b * NN + qq] : 0.f;
      w[t] = (d > 0.f) ? 1.f / d : 0.f;
    }
    __syncthreads();
    f32x16 s;
    #pragma unroll
    for (int i = 0; i < 16; ++i) s[i] = 0.f;
    #pragma unroll
    for (int ks = 0; ks < 4; ++ks) {
      short8 a  = *(const short8*)&lk[(kh * 32 + l31) * LS + ks * 16 + lhi * 8];
      short8 bq = *(const short8*)&lq[(qh * 32 + l31) * LS + ks * 16 + lhi * 8];
      s = __builtin_amdgcn_mfma_f32_32x32x16_bf16(a, bq, s, 0, 0, 0);
    }
    float wq = w[qh * 32 + l31];
    #pragma unroll
    for (int reg = 0; reg < 16; ++reg) vacc[reg] += __expf(20.f * s[reg]) * wq;
  }
  #pragma unroll
  for (int reg = 0; reg < 16; ++reg) {
    float v = vacc[reg];
    v += __shfl_xor(v, 1); v += __shfl_xor(v, 2); v += __shfl_xor(v, 4);
    v += __shfl_xor(v, 8); v += __shfl_xor(v, 16);
    int row = (reg & 3) + 8 * (reg >> 2) + 4 * lhi;
    int kk = k0 + kh * 32 + row;
    if (l31 == 0 && kk < nkb) atomicAdd(&vis[b * NN + kix[kk]], v);
  }
}

// -------- 9a. default out = x (fp32 bit copy, 4 MB) ------------------------
__global__ __launch_bounds__(256) void k_copy(const uint4* __restrict__ src, uint4* __restrict__ dst, int n) {
  int i = blockIdx.x * 256 + threadIdx.x;
  if (i < n) dst[i] = src[i];
}

// -------- 9b. fusion epilogue: MFMA over 64-q blocks -----------------------
#define FS 136            // pxa row stride (bf16)
__global__ __launch_bounds__(256) void k_fusionm(const unsigned short* __restrict__ xt,
                                                 const float* __restrict__ afc,
                                                 const float* __restrict__ den,
                                                 const int* __restrict__ qidx, const int* __restrict__ nqv,
                                                 const unsigned short* __restrict__ wall,
                                                 const float* __restrict__ b2,
                                                 float* __restrict__ outp) {
  int b = blockIdx.y;
  int nqb = nqv[b];
  int q0 = blockIdx.x * 64;
  if (q0 >= nqb) return;
  __shared__ unsigned short pxa[64 * FS];   // [q][128] px|pa, 17.4 KB
  __shared__ unsigned short f1s[64 * LS];   // [q][co], 9.2 KB
  __shared__ int qpl[64];
  int t = threadIdx.x;
  int lane = t & 63;
  int quad = lane >> 4, col = lane & 15;
  int cb = (t >> 6) * 16;                   // wave's co strip
  const int* qix = qidx + b * NN;
  const unsigned short* xtb = xt + (size_t)b * NN * 64;
  const unsigned short* w1b = wall;
  const unsigned short* w2b = wall + 8192;
  const unsigned short* wfb = wall + 12288;
  short8 a1[4], a2[2], af[4];
  #pragma unroll
  for (int kt = 0; kt < 4; ++kt) {
    a1[kt] = *(const short8*)&w1b[(cb + col) * 128 + kt * 32 + quad * 8];
    af[kt] = *(const short8*)&wfb[(cb + col) * 128 + kt * 32 + quad * 8];
  }
  #pragma unroll
  for (int kt = 0; kt < 2; ++kt)
    a2[kt] = *(const short8*)&w2b[(cb + col) * 64 + kt * 32 + quad * 8];
  float b2v[4];
  #pragma unroll
  for (int r = 0; r < 4; ++r) b2v[r] = b2[cb + quad * 4 + r];
  if (t < 64) qpl[t] = (q0 + t < nqb) ? qix[q0 + t] : -1;
  for (int idx = t; idx < 512; idx += 256) {
    int q = idx >> 3, c8 = (idx & 7) * 8;
    int qq = q0 + q;
    uint4 pv = make_uint4(0u, 0u, 0u, 0u);
    unsigned short pa8[8] = {0, 0, 0, 0, 0, 0, 0, 0};
    if (qq < nqb) {
      int qp = qix[qq];
      pv = *(const uint4*)(xtb + (size_t)qp * 64 + c8);
      float d = den[b * NN + qq];
      float invd = (d > 0.f) ? 1.f / d : 0.f;
      const float* ap = afc + ((size_t)b * NN + qq) * 64 + c8;
      #pragma unroll
      for (int j = 0; j < 8; ++j) pa8[j] = f2bu(ap[j] * invd);
    }
    *(uint4*)&pxa[q * FS + c8] = pv;
    *(uint4*)&pxa[q * FS + 64 + c8] = *(const uint4*)&pa8[0];
  }
  __syncthreads();
  #pragma unroll
  for (int qt = 0; qt < 4; ++qt) {
    f32x4 acc = {0.f, 0.f, 0.f, 0.f};
    #pragma unroll
    for (int kt = 0; kt < 4; ++kt) {
      short8 bfrag = *(const short8*)&pxa[(qt * 16 + col) * FS + kt * 32 + quad * 8];
      acc = __builtin_amdgcn_mfma_f32_16x16x32_bf16(a1[kt], bfrag, acc, 0, 0, 0);
    }
    #pragma unroll
    for (int r = 0; r < 4; ++r)
      f1s[(qt * 16 + col) * LS + cb + quad * 4 + r] = f2bu(acc[r]);
  }
  __syncthreads();
  #pragma unroll
  for (int qt = 0; qt < 4; ++qt) {
    f32x4 acc = {0.f, 0.f, 0.f, 0.f};
    #pragma unroll
    for (int kt = 0; kt < 2; ++kt) {
      short8 bfrag = *(const short8*)&f1s[(qt * 16 + col) * LS + kt * 32 + quad * 8];
      acc = __builtin_amdgcn_mfma_f32_16x16x32_bf16(a2[kt], bfrag, acc, 0, 0, 0);
    }
    #pragma unroll
    for (int r = 0; r < 4; ++r) {
      float sg = 1.f / (1.f + __expf(-(acc[r] + b2v[r])));
      int addr = (qt * 16 + col) * FS + 64 + cb + quad * 4 + r;
      pxa[addr] = f2bu(us2f(pxa[addr]) * (1.f - sg));
    }
  }
  __syncthreads();
  #pragma unroll
  for (int qt = 0; qt < 4; ++qt) {
    f32x4 acc = {0.f, 0.f, 0.f, 0.f};
    #pragma unroll
    for (int kt = 0; kt < 4; ++kt) {
      short8 bfrag = *(const short8*)&pxa[(qt * 16 + col) * FS + kt * 32 + quad * 8];
      acc = __builtin_amdgcn_mfma_f32_16x16x32_bf16(af[kt], bfrag, acc, 0, 0, 0);
    }
    int qp = qpl[qt * 16 + col];
    if (qp >= 0) {
      #pragma unroll
      for (int r = 0; r < 4; ++r)
        outp[((size_t)b * CC + cb + quad * 4 + r) * NN + qp] = acc[r];
    }
  }
}

// -------- 10a. global max of visatt ----------------------------------------
__global__ __launch_bounds__(256) void k_vmax(const float* __restrict__ vis, unsigned int* __restrict__ vmaxb) {
  int i = blockIdx.x * 256 + threadIdx.x;
  float v = vis[i];
  #pragma unroll
  for (int off = 32; off > 0; off >>= 1) v = fmaxf(v, __shfl_down(v, off));
  if ((threadIdx.x & 63) == 0) atomicMax(vmaxb, __float_as_uint(v));
}

// -------- 10b. x8 nearest upsample + normalize -----------------------------
__global__ __launch_bounds__(256) void k_upsample(const float* __restrict__ vis,
                                                  const unsigned int* __restrict__ vmaxb,
                                                  float* __restrict__ out2) {
  int i = blockIdx.x * 256 + threadIdx.x;
  int b = i >> 18;
  int rem = i & 262143;
  int y = rem >> 9, x = rem & 511;
  float vm = __uint_as_float(vmaxb[0]);
  if (!(vm > 0.f)) vm = 1.f;
  out2[i] = vis[b * NN + (y >> 3) * 64 + (x >> 3)] / vm;
}

extern "C" void kernel_launch(void* const* d_in, const int* in_sizes, int n_in,
                              void* d_out, int out_size, void* d_ws, size_t ws_size,
                              hipStream_t stream) {
  const float* x    = (const float*)d_in[0];
  const float* mask = (const float*)d_in[1];
  const float* w1   = (const float*)d_in[2];
  const float* w2c  = (const float*)d_in[3];
  const float* fsw1 = (const float*)d_in[4];
  const float* fsw2 = (const float*)d_in[5];
  const float* fsb2 = (const float*)d_in[6];
  const float* fswf = (const float*)d_in[7];
  float* out = (float*)d_out;
  char* wsb = (char*)d_ws;

  float* afc = (float*)(wsb + WB_AFC);
  float* den = (float*)(wsb + WB_DEN);
  float* vis = (float*)(wsb + WB_VIS);
  int* qidx  = (int*)(wsb + WB_QIX);
  int* kidx  = (int*)(wsb + WB_KIX);
  unsigned char* mfl = (unsigned char*)(wsb + WB_MFL);
  int* nq = (int*)(wsb + WB_CNT);
  int* nk = nq + 4;
  unsigned int* vmaxb = (unsigned int*)(nq + 8);
  float* gstat = (float*)(wsb + WB_STAT);
  float* gsum1 = gstat;
  float* gsq1  = gstat + 256;
  float* gsum2 = gstat + 512;
  float* gsq2  = gstat + 768;
  unsigned short* wT1 = (unsigned short*)(wsb + WB_WT1);
  unsigned short* wT2 = (unsigned short*)(wsb + WB_WT2);
  unsigned short* wall = (unsigned short*)(wsb + WB_WFB);
  unsigned short* y1t = (unsigned short*)(wsb + WB_AFC);   // 2 MB, dead before k_knorm zeroes afc

  // scratch staged inside d_out:
  unsigned short* kxt = (unsigned short*)out;
  unsigned short* khat = kxt;
  unsigned short* xt = (unsigned short*)(out + 1048576);

  k_maxpool<<<256, 256, 0, stream>>>(mask, mfl, vis, gstat, vmaxb);
  k_compact<<<4, 64, 0, stream>>>(mfl, qidx, kidx, nq, nk);
  k_xT<<<256, 256, 0, stream>>>(x, xt);
  k_wprep<<<224, 256, 0, stream>>>(w1, w2c, fsw1, fsw2, fswf, wT1, wT2, wall);
  k_convm<false><<<dim3(64, BB), 256, 0, stream>>>(xt, wT1, nullptr, nullptr, y1t, gsum1, gsq1);
  k_convm<true><<<dim3(64, BB), 256, 0, stream>>>(y1t, wT2, gsum1, gsq1, kxt, gsum2, gsq2);
  k_knorm<<<256, 256, 0, stream>>>(kxt, xt, gsum2, gsq2, afc, den);
  k_att1<<<dim3(256, BB), 256, 0, stream>>>(khat, xt, qidx, kidx, nq, nk, afc, den);
  k_att2<<<dim3(256, BB), 256, 0, stream>>>(khat, qidx, kidx, nq, nk, den, vis);
  k_copy<<<1024, 256, 0, stream>>>((const uint4*)x, (uint4*)out, 262144);
  k_fusionm<<<dim3(64, BB), 256, 0, stream>>>(xt, afc, den, qidx, nq, wall, fsb2, out);
  k_vmax<<<64, 256, 0, stream>>>(vis, vmaxb);
  k_upsample<<<4096, 256, 0, stream>>>(vis, vmaxb, out + 1048576);
}

// Round 13
// 192.399 us; speedup vs baseline: 1.0426x; 1.0426x over previous
//
#include <hip/hip_runtime.h>
#include <hip/hip_bf16.h>

typedef __hip_bfloat16 bf16;
typedef __attribute__((ext_vector_type(8))) short short8;
typedef __attribute__((ext_vector_type(4))) float f32x4;
typedef __attribute__((ext_vector_type(16))) float f32x16;

#define BB 4
#define CC 64
#define NN 4096           // 64*64
#define MH 512
#define MW 512
#define LS 72             // LDS row stride in bf16 elements

// ---- workspace layout (BYTE offsets; total ~4.67 MiB) ----
#define WB_AFC  ((size_t)0)         // f32[4*4096*64] att_fore UNNORMALIZED sums (atomic)
                                    // first 2 MB double as y1t (bf16 conv1 raw) before k_knorm
#define WB_DEN  ((size_t)4194304)   // f32[4*4096] softmax denominators (atomic)
#define WB_VIS  ((size_t)4259840)   // f32[4*4096] visatt (atomic)
#define WB_QIX  ((size_t)4325376)   // int[4*4096]
#define WB_KIX  ((size_t)4390912)   // int[4*4096]
#define WB_MFL  ((size_t)4456448)   // uchar[4*4096]
#define WB_CNT  ((size_t)4472832)   // int nq[4]; int nk[4]; uint vmaxbits (12 ints)
#define WB_STAT ((size_t)4472896)   // f32 gsum1[256]; gsq1[256]; gsum2[256]; gsq2[256]
#define WB_WT1  ((size_t)4476992)   // bf16[9*64*64] wT1
#define WB_WT2  ((size_t)4550720)   // bf16[9*64*64] wT2
#define WB_WFB  ((size_t)4624448)   // bf16 w1b[8192]; w2b[4096]; wfb[8192] (40960 B)

__device__ __forceinline__ float b2f(bf16 v) { return __bfloat162float(v); }
__device__ __forceinline__ float us2f(unsigned short u) { return __uint_as_float(((unsigned)u) << 16); }
__device__ __forceinline__ unsigned short f2bu(float f) {
  bf16 h = __float2bfloat16(f);
  return *(unsigned short*)&h;
}

// ------- 1. maxpool 8x8 on mask (4 lanes/window) + zero vis/stats/vmax -----
__global__ __launch_bounds__(256) void k_maxpool(const float* __restrict__ mask,
                                                 unsigned char* __restrict__ mfl,
                                                 float* __restrict__ vis,
                                                 float* __restrict__ gstat,
                                                 unsigned int* __restrict__ vmaxb) {
  int g = blockIdx.x * 256 + threadIdx.x;          // < 4*4096*4
  int o = g >> 2, sub = g & 3;
  int b = o >> 12, p = o & 4095;
  int py = p >> 6, px = p & 63;
  const float* mb = mask + (size_t)b * MH * MW + (py * 8 + sub * 2) * MW + px * 8;
  float mx = 0.f;
  #pragma unroll
  for (int dy = 0; dy < 2; ++dy) {
    const float4* r4 = (const float4*)(mb + dy * MW);
    float4 a = r4[0], c = r4[1];
    mx = fmaxf(mx, fmaxf(fmaxf(a.x, a.y), fmaxf(a.z, a.w)));
    mx = fmaxf(mx, fmaxf(fmaxf(c.x, c.y), fmaxf(c.z, c.w)));
  }
  mx = fmaxf(mx, __shfl_xor(mx, 1));
  mx = fmaxf(mx, __shfl_xor(mx, 2));
  if (sub == 0) {
    mfl[o] = (mx > 0.f) ? 1 : 0;
    vis[o] = 0.f;
  }
  if (g < 1024) gstat[g] = 0.f;
  if (g == 0) vmaxb[0] = 0u;
}

// ---------------- 2. fg/bg index compaction (1 wave per batch) -------------
__global__ __launch_bounds__(64) void k_compact(const unsigned char* __restrict__ mfl,
                                                int* __restrict__ qidx, int* __restrict__ kidx,
                                                int* __restrict__ nq, int* __restrict__ nk) {
  int b = blockIdx.x, lane = threadIdx.x;
  int qb = 0, kb = 0;
  for (int it = 0; it < 64; ++it) {
    int p = it * 64 + lane;
    bool f = mfl[b * NN + p] != 0;
    unsigned long long bal = __ballot(f);
    int before = __popcll(bal & ((1ULL << lane) - 1ULL));
    if (f)  qidx[b * NN + qb + before] = p;
    if (!f) kidx[b * NN + kb + (lane - before)] = p;
    int cnt = __popcll(bal);
    qb += cnt; kb += 64 - cnt;
  }
  if (lane == 0) { nq[b] = qb; nk[b] = kb; }
}

// -------- 3. transpose x -> bf16 pixel-major (xt) --------------------------
__global__ __launch_bounds__(256) void k_xT(const float* __restrict__ x,
                                            unsigned short* __restrict__ xt) {
  int b = blockIdx.x >> 6, p0 = (blockIdx.x & 63) * 64;
  __shared__ float lx[64][65];
  int t = threadIdx.x;
  const float* xb = x + (size_t)b * CC * NN + p0;
  for (int idx = t; idx < 4096; idx += 256) {
    int c = idx >> 6, j = idx & 63;
    lx[j][c] = xb[c * NN + j];
  }
  __syncthreads();
  unsigned short* xo = xt + ((size_t)b * NN + p0) * 64;
  for (int idx = t; idx < 2048; idx += 256) {
    int j = idx >> 5, c2 = (idx & 31) * 2;
    ushort2 w2;
    w2.x = f2bu(lx[j][c2]);
    w2.y = f2bu(lx[j][c2 + 1]);
    *(ushort2*)&xo[j * 64 + c2] = w2;
  }
}

// -------- 4. weight prep: conv wT + fusion weights -> bf16 -----------------
__global__ __launch_bounds__(256) void k_wprep(const float* __restrict__ w1,
                                               const float* __restrict__ w2,
                                               const float* __restrict__ fw1,
                                               const float* __restrict__ fw2,
                                               const float* __restrict__ fwf,
                                               unsigned short* __restrict__ wT1,
                                               unsigned short* __restrict__ wT2,
                                               unsigned short* __restrict__ wfb) {
  int i = blockIdx.x * 256 + threadIdx.x;   // < 57344
  if (i < 36864) {
    int tap = i >> 12;
    int rem = i & 4095;
    int co = rem >> 6, ci = rem & 63;
    int src = (co * 64 + ci) * 9 + tap;
    wT1[i] = f2bu(w1[src]);
    wT2[i] = f2bu(w2[src]);
  } else if (i < 57344) {
    int j = i - 36864;
    if (j < 8192)       wfb[j] = f2bu(fw1[j]);                 // w1b
    else if (j < 12288) wfb[j] = f2bu(fw2[j - 8192]);          // w2b
    else                wfb[j] = f2bu(fwf[j - 12288]);         // wfb
  }
}

// -------- 5. MFMA conv3x3(pad1) as 9 row-gathered GEMMs --------------------
template <bool NORM_IN>
__global__ __launch_bounds__(256) void k_convm(const unsigned short* __restrict__ src,
                                               const unsigned short* __restrict__ wT,
                                               const float* __restrict__ insum,
                                               const float* __restrict__ insq,
                                               unsigned short* __restrict__ dst,
                                               float* __restrict__ gsum,
                                               float* __restrict__ gsq) {
  int b = blockIdx.y;
  int r = blockIdx.x;              // image row 0..63
  __shared__ unsigned short bx[198 * LS];   // 28.5 KB
  __shared__ float nmean[64], ninv[64];
  int t = threadIdx.x;
  if (NORM_IN) {
    if (t < 64) {
      float m = insum[b * 64 + t] * (1.f / NN);
      float v = fmaxf(insq[b * 64 + t] * (1.f / NN) - m * m, 0.f);
      nmean[t] = m; ninv[t] = rsqrtf(v + 1e-5f);
    }
    __syncthreads();
  }
  const unsigned short* sb = src + (size_t)b * NN * 64;
  for (int idx = t; idx < 198 * 8; idx += 256) {
    int row = idx >> 3, c8 = (idx & 7) * 8;
    int dy = row / 66;
    int cx = row - dy * 66 - 1;
    int rr = r + dy - 1;
    uint4 v = make_uint4(0u, 0u, 0u, 0u);
    if ((unsigned)rr < 64u && (unsigned)cx < 64u) {
      v = *(const uint4*)(sb + ((size_t)(rr * 64 + cx)) * 64 + c8);
      if (NORM_IN) {
        unsigned short* e = (unsigned short*)&v;
        #pragma unroll
        for (int j = 0; j < 8; ++j)
          e[j] = f2bu(fmaxf((us2f(e[j]) - nmean[c8 + j]) * ninv[c8 + j], 0.f));
      }
    }
    *(uint4*)&bx[row * LS + c8] = v;
  }
  __syncthreads();
  int lane = t & 63;
  int quad = lane >> 4, col = lane & 15;
  int qw = (t >> 6) * 16;          // co strip
  f32x4 acc[4] = {{0.f,0.f,0.f,0.f},{0.f,0.f,0.f,0.f},{0.f,0.f,0.f,0.f},{0.f,0.f,0.f,0.f}};
  #pragma unroll
  for (int tap = 0; tap < 9; ++tap) {
    int dy = tap / 3, dx = tap - dy * 3 - 1;
    const unsigned short* wrow = wT + ((size_t)tap * 64 + qw + col) * 64;
    short8 a0 = *(const short8*)(wrow + quad * 8);
    short8 a1 = *(const short8*)(wrow + 32 + quad * 8);
    int rbase = dy * 66 + dx + 1;
    #pragma unroll
    for (int nt = 0; nt < 4; ++nt) {
      int row = rbase + nt * 16 + col;
      short8 b0 = *(const short8*)&bx[row * LS + quad * 8];
      short8 b1 = *(const short8*)&bx[row * LS + 32 + quad * 8];
      acc[nt] = __builtin_amdgcn_mfma_f32_16x16x32_bf16(a0, b0, acc[nt], 0, 0, 0);
      acc[nt] = __builtin_amdgcn_mfma_f32_16x16x32_bf16(a1, b1, acc[nt], 0, 0, 0);
    }
  }
  #pragma unroll
  for (int rr = 0; rr < 4; ++rr) {
    float s1 = acc[0][rr] + acc[1][rr] + acc[2][rr] + acc[3][rr];
    float s2 = acc[0][rr]*acc[0][rr] + acc[1][rr]*acc[1][rr]
             + acc[2][rr]*acc[2][rr] + acc[3][rr]*acc[3][rr];
    s1 += __shfl_xor(s1, 1); s2 += __shfl_xor(s2, 1);
    s1 += __shfl_xor(s1, 2); s2 += __shfl_xor(s2, 2);
    s1 += __shfl_xor(s1, 4); s2 += __shfl_xor(s2, 4);
    s1 += __shfl_xor(s1, 8); s2 += __shfl_xor(s2, 8);
    if (col == 0) {
      int co = qw + quad * 4 + rr;
      atomicAdd(&gsum[b * 64 + co], s1);
      atomicAdd(&gsq[b * 64 + co], s2);
    }
  }
  __syncthreads();
  #pragma unroll
  for (int nt = 0; nt < 4; ++nt)
    #pragma unroll
    for (int rr = 0; rr < 4; ++rr)
      bx[(nt * 16 + col) * LS + qw + quad * 4 + rr] = f2bu(acc[nt][rr]);
  __syncthreads();
  unsigned short* db = dst + ((size_t)b * NN + r * 64) * 64;
  for (int idx = t; idx < 512; idx += 256) {
    int px = idx >> 3, c8 = (idx & 7) * 8;
    *(uint4*)(db + (size_t)px * 64 + c8) = *(const uint4*)&bx[px * LS + c8];
  }
}

// -------- 6. fused inorm2 + residual + relu + L2-norm; zero afc/den --------
__global__ __launch_bounds__(256) void k_knorm(unsigned short* __restrict__ kxt,
                                               const unsigned short* __restrict__ xt,
                                               const float* __restrict__ gsum,
                                               const float* __restrict__ gsq,
                                               float* __restrict__ afc,
                                               float* __restrict__ den) {
  int b = blockIdx.x >> 6;
  int p0 = (blockIdx.x & 63) * 64;
  __shared__ float m2[64], i2[64];
  int t = threadIdx.x;
  if (t < 64) {
    float m = gsum[b * 64 + t] * (1.f / NN);
    float v = fmaxf(gsq[b * 64 + t] * (1.f / NN) - m * m, 0.f);
    m2[t] = m; i2[t] = rsqrtf(v + 1e-5f);
  }
  size_t gid = (size_t)blockIdx.x * 256 + t;
  float4 z4 = make_float4(0.f, 0.f, 0.f, 0.f);
  float4* az = (float4*)afc;
  #pragma unroll
  for (int j = 0; j < 4; ++j) az[gid + (size_t)j * 65536] = z4;
  if (gid < 16384) den[gid] = 0.f;
  __syncthreads();
  int px = t >> 2, c0 = (t & 3) * 16;
  size_t base = ((size_t)b * NN + p0 + px) * 64 + c0;
  unsigned short kv[16], xv[16];
  *(uint4*)&kv[0] = *(const uint4*)(kxt + base);
  *(uint4*)&kv[8] = *(const uint4*)(kxt + base + 8);
  *(uint4*)&xv[0] = *(const uint4*)(xt + base);
  *(uint4*)&xv[8] = *(const uint4*)(xt + base + 8);
  float v[16]; float ss = 0.f;
  #pragma unroll
  for (int j = 0; j < 16; ++j) {
    float f = fmaxf((us2f(kv[j]) - m2[c0 + j]) * i2[c0 + j] + us2f(xv[j]), 0.f);
    v[j] = f; ss += f * f;
  }
  ss += __shfl_xor(ss, 1);
  ss += __shfl_xor(ss, 2);
  float inv = 1.f / (sqrtf(ss) + 1e-8f);
  #pragma unroll
  for (int j = 0; j < 16; ++j) kv[j] = f2bu(v[j] * inv);
  *(uint4*)(kxt + base) = *(const uint4*)&kv[0];
  *(uint4*)(kxt + base + 8) = *(const uint4*)&kv[8];
}

// -------- 7. attention pass 1: 32x32 MFMA, K-split x8, Q-frags in regs -----
__global__ __launch_bounds__(256) void k_att1(const unsigned short* __restrict__ khat,
                                              const unsigned short* __restrict__ xt,
                                              const int* __restrict__ qidx, const int* __restrict__ kidx,
                                              const int* __restrict__ nqv, const int* __restrict__ nkv,
                                              float* __restrict__ afc, float* __restrict__ den) {
  int b = blockIdx.y;
  int nqb = nqv[b], nkb = nkv[b];
  int q0 = (blockIdx.x >> 3) * 64;
  int part = blockIdx.x & 7;
  if (q0 >= nqb) return;
  int kbeg = (part * nkb) >> 3;
  int kend = ((part + 1) * nkb) >> 3;
  __shared__ unsigned short lk [64 * LS];   // K   [k][c]
  __shared__ unsigned short lvT[64 * LS];   // V^T [c][k-swizzled]
  __shared__ unsigned short le [64 * LS];   // E   [q][k]
  int t = threadIdx.x;
  int wave = t >> 6, lane = t & 63;
  int l31 = lane & 31, lhi = lane >> 5;
  int qh = wave >> 1, kh = wave & 1;
  const int* qix = qidx + b * NN;
  const int* kix = kidx + b * NN;
  const unsigned short* khb = khat + (size_t)b * NN * 64;
  const unsigned short* xtb = xt + (size_t)b * NN * 64;
  // Q A-fragments in registers (loop-invariant; per-lane row gather, L2-hit)
  int qq_a = q0 + qh * 32 + l31;
  int qp_a = (qq_a < nqb) ? qix[qq_a] : qix[0];
  short8 aq[4];
  #pragma unroll
  for (int ks = 0; ks < 4; ++ks)
    aq[ks] = *(const short8*)(khb + (size_t)qp_a * 64 + ks * 16 + lhi * 8);
  f32x16 pv, dsum;
  #pragma unroll
  for (int i = 0; i < 16; ++i) { pv[i] = 0.f; dsum[i] = 0.f; }
  int kp2 = t >> 3, vc8 = (t & 7) * 8, vcc = (t & 7);
  for (int j0 = kbeg; j0 < kend; j0 += 64) {
    __syncthreads();
    for (int idx = t; idx < 512; idx += 256) {
      int k = idx >> 3, c8 = (idx & 7) * 8;
      uint4 v = make_uint4(0u, 0u, 0u, 0u);
      if (j0 + k < kend) v = *(const uint4*)(khb + (size_t)kix[j0 + k] * 64 + c8);
      *(uint4*)&lk[k * LS + c8] = v;
    }
    {
      uint4 v0 = make_uint4(0u, 0u, 0u, 0u);
      uint4 v1 = make_uint4(0u, 0u, 0u, 0u);
      int ka = j0 + 2 * kp2, kb2 = ka + 1;
      if (ka  < kend) v0 = *(const uint4*)(xtb + (size_t)kix[ka]  * 64 + vc8);
      if (kb2 < kend) v1 = *(const uint4*)(xtb + (size_t)kix[kb2] * 64 + vc8);
      const unsigned short* e0 = (const unsigned short*)&v0;
      const unsigned short* e1 = (const unsigned short*)&v1;
      int pbase = kp2 & 3, prun = kp2 >> 2;
      int pp = pbase + ((prun ^ vcc) << 2);
      #pragma unroll
      for (int jj = 0; jj < 8; ++jj) {
        int c = vc8 + jj;
        unsigned int w2 = (unsigned)e0[jj] | ((unsigned)e1[jj] << 16);
        *(unsigned int*)&lvT[c * LS + pp * 2] = w2;
      }
    }
    __syncthreads();
    // QK: quadrant (qh, kh)
    f32x16 s;
    #pragma unroll
    for (int i = 0; i < 16; ++i) s[i] = 0.f;
    #pragma unroll
    for (int ks = 0; ks < 4; ++ks) {
      short8 bk = *(const short8*)&lk[(kh * 32 + l31) * LS + ks * 16 + lhi * 8];
      s = __builtin_amdgcn_mfma_f32_32x32x16_bf16(aq[ks], bk, s, 0, 0, 0);
    }
    bool kval = (j0 + kh * 32 + l31) < kend;
    #pragma unroll
    for (int reg = 0; reg < 16; ++reg) {
      float e = kval ? __expf(20.f * s[reg]) : 0.f;
      dsum[reg] += e;
      int row = (reg & 3) + 8 * (reg >> 2) + 4 * lhi;
      le[(qh * 32 + row) * LS + kh * 32 + l31] = f2bu(e);
    }
    __syncthreads();
    // PV: quadrant (qh, ch=kh)
    int c = kh * 32 + l31;
    int c37 = (c >> 3) & 7;
    #pragma unroll
    for (int ks = 0; ks < 4; ++ks) {
      short8 a  = *(const short8*)&le[(qh * 32 + l31) * LS + ks * 16 + lhi * 8];
      int run = ks * 2 + lhi;
      short8 bv = *(const short8*)&lvT[c * LS + ((run ^ c37) << 3)];
      pv = __builtin_amdgcn_mfma_f32_32x32x16_bf16(a, bv, pv, 0, 0, 0);
    }
  }
  #pragma unroll
  for (int reg = 0; reg < 16; ++reg) {
    float v = dsum[reg];
    v += __shfl_xor(v, 1); v += __shfl_xor(v, 2); v += __shfl_xor(v, 4);
    v += __shfl_xor(v, 8); v += __shfl_xor(v, 16);
    int row = (reg & 3) + 8 * (reg >> 2) + 4 * lhi;
    int qq = q0 + qh * 32 + row;
    if (l31 == 0 && qq < nqb) atomicAdd(&den[b * NN + qq], v);
  }
  #pragma unroll
  for (int reg = 0; reg < 16; ++reg) {
    int row = (reg & 3) + 8 * (reg >> 2) + 4 * lhi;
    int qq = q0 + qh * 32 + row;
    if (qq < nqb) atomicAdd(&afc[((size_t)b * NN + qq) * 64 + kh * 32 + l31], pv[reg]);
  }
}

// -------- 8. attention pass 2: 32x32 MFMA, Q-split x8, K-frags in regs -----
__global__ __launch_bounds__(256) void k_att2(const unsigned short* __restrict__ khat,
                                              const int* __restrict__ qidx, const int* __restrict__ kidx,
                                              const int* __restrict__ nqv, const int* __restrict__ nkv,
                                              const float* __restrict__ den, float* __restrict__ vis) {
  int b = blockIdx.y;
  int nqb = nqv[b], nkb = nkv[b];
  int k0 = (blockIdx.x >> 3) * 64;
  int part = blockIdx.x & 7;
  if (k0 >= nkb) return;
  int qbeg = (part * nqb) >> 3;
  int qend = ((part + 1) * nqb) >> 3;
  __shared__ unsigned short lq[64 * LS];
  __shared__ float w[64];
  int t = threadIdx.x;
  int wave = t >> 6, lane = t & 63;
  int l31 = lane & 31, lhi = lane >> 5;
  int kh = wave >> 1, qh = wave & 1;
  const int* qix = qidx + b * NN;
  const int* kix = kidx + b * NN;
  const unsigned short* khb = khat + (size_t)b * NN * 64;
  // K A-fragments in registers (loop-invariant)
  int kk_a = k0 + kh * 32 + l31;
  int kp_a = (kk_a < nkb) ? kix[kk_a] : kix[0];
  short8 ak[4];
  #pragma unroll
  for (int ks = 0; ks < 4; ++ks)
    ak[ks] = *(const short8*)(khb + (size_t)kp_a * 64 + ks * 16 + lhi * 8);
  f32x16 vacc;
  #pragma unroll
  for (int i = 0; i < 16; ++i) vacc[i] = 0.f;
  for (int i0 = qbeg; i0 < qend; i0 += 64) {
    __syncthreads();
    for (int idx = t; idx < 512; idx += 256) {
      int q = idx >> 3, c8 = (idx & 7) * 8;
      uint4 v = make_uint4(0u, 0u, 0u, 0u);
      if (i0 + q < qend) v = *(const uint4*)(khb + (size_t)qix[i0 + q] * 64 + c8);
      *(uint4*)&lq[q * LS + c8] = v;
    }
    if (t < 64) {
      int qq = i0 + t;
      float d = (qq < qend) ? den[b * NN + qq] : 0.f;
      w[t] = (d > 0.f) ? 1.f / d : 0.f;
    }
    __syncthreads();
    f32x16 s;
    #pragma unroll
    for (int i = 0; i < 16; ++i) s[i] = 0.f;
    #pragma unroll
    for (int ks = 0; ks < 4; ++ks) {
      short8 bq = *(const short8*)&lq[(qh * 32 + l31) * LS + ks * 16 + lhi * 8];
      s = __builtin_amdgcn_mfma_f32_32x32x16_bf16(ak[ks], bq, s, 0, 0, 0);
    }
    float wq = w[qh * 32 + l31];
    #pragma unroll
    for (int reg = 0; reg < 16; ++reg) vacc[reg] += __expf(20.f * s[reg]) * wq;
  }
  #pragma unroll
  for (int reg = 0; reg < 16; ++reg) {
    float v = vacc[reg];
    v += __shfl_xor(v, 1); v += __shfl_xor(v, 2); v += __shfl_xor(v, 4);
    v += __shfl_xor(v, 8); v += __shfl_xor(v, 16);
    int row = (reg & 3) + 8 * (reg >> 2) + 4 * lhi;
    int kk = k0 + kh * 32 + row;
    if (l31 == 0 && kk < nkb) atomicAdd(&vis[b * NN + kix[kk]], v);
  }
}

// -------- 9a. default out = x (fp32 bit copy, 4 MB) ------------------------
__global__ __launch_bounds__(256) void k_copy(const uint4* __restrict__ src, uint4* __restrict__ dst, int n) {
  int i = blockIdx.x * 256 + threadIdx.x;
  if (i < n) dst[i] = src[i];
}

// -------- 9b. fusion epilogue: MFMA over 64-q blocks -----------------------
#define FS 136            // pxa row stride (bf16)
__global__ __launch_bounds__(256) void k_fusionm(const unsigned short* __restrict__ xt,
                                                 const float* __restrict__ afc,
                                                 const float* __restrict__ den,
                                                 const int* __restrict__ qidx, const int* __restrict__ nqv,
                                                 const unsigned short* __restrict__ wall,
                                                 const float* __restrict__ b2,
                                                 float* __restrict__ outp) {
  int b = blockIdx.y;
  int nqb = nqv[b];
  int q0 = blockIdx.x * 64;
  if (q0 >= nqb) return;
  __shared__ unsigned short pxa[64 * FS];   // [q][128] px|pa, 17.4 KB
  __shared__ unsigned short f1s[64 * LS];   // [q][co], 9.2 KB
  __shared__ int qpl[64];
  int t = threadIdx.x;
  int lane = t & 63;
  int quad = lane >> 4, col = lane & 15;
  int cb = (t >> 6) * 16;                   // wave's co strip
  const int* qix = qidx + b * NN;
  const unsigned short* xtb = xt + (size_t)b * NN * 64;
  const unsigned short* w1b = wall;
  const unsigned short* w2b = wall + 8192;
  const unsigned short* wfb = wall + 12288;
  short8 a1[4], a2[2], af[4];
  #pragma unroll
  for (int kt = 0; kt < 4; ++kt) {
    a1[kt] = *(const short8*)&w1b[(cb + col) * 128 + kt * 32 + quad * 8];
    af[kt] = *(const short8*)&wfb[(cb + col) * 128 + kt * 32 + quad * 8];
  }
  #pragma unroll
  for (int kt = 0; kt < 2; ++kt)
    a2[kt] = *(const short8*)&w2b[(cb + col) * 64 + kt * 32 + quad * 8];
  float b2v[4];
  #pragma unroll
  for (int r = 0; r < 4; ++r) b2v[r] = b2[cb + quad * 4 + r];
  if (t < 64) qpl[t] = (q0 + t < nqb) ? qix[q0 + t] : -1;
  for (int idx = t; idx < 512; idx += 256) {
    int q = idx >> 3, c8 = (idx & 7) * 8;
    int qq = q0 + q;
    uint4 pv = make_uint4(0u, 0u, 0u, 0u);
    unsigned short pa8[8] = {0, 0, 0, 0, 0, 0, 0, 0};
    if (qq < nqb) {
      int qp = qix[qq];
      pv = *(const uint4*)(xtb + (size_t)qp * 64 + c8);
      float d = den[b * NN + qq];
      float invd = (d > 0.f) ? 1.f / d : 0.f;
      const float* ap = afc + ((size_t)b * NN + qq) * 64 + c8;
      #pragma unroll
      for (int j = 0; j < 8; ++j) pa8[j] = f2bu(ap[j] * invd);
    }
    *(uint4*)&pxa[q * FS + c8] = pv;
    *(uint4*)&pxa[q * FS + 64 + c8] = *(const uint4*)&pa8[0];
  }
  __syncthreads();
  #pragma unroll
  for (int qt = 0; qt < 4; ++qt) {
    f32x4 acc = {0.f, 0.f, 0.f, 0.f};
    #pragma unroll
    for (int kt = 0; kt < 4; ++kt) {
      short8 bfrag = *(const short8*)&pxa[(qt * 16 + col) * FS + kt * 32 + quad * 8];
      acc = __builtin_amdgcn_mfma_f32_16x16x32_bf16(a1[kt], bfrag, acc, 0, 0, 0);
    }
    #pragma unroll
    for (int r = 0; r < 4; ++r)
      f1s[(qt * 16 + col) * LS + cb + quad * 4 + r] = f2bu(acc[r]);
  }
  __syncthreads();
  #pragma unroll
  for (int qt = 0; qt < 4; ++qt) {
    f32x4 acc = {0.f, 0.f, 0.f, 0.f};
    #pragma unroll
    for (int kt = 0; kt < 2; ++kt) {
      short8 bfrag = *(const short8*)&f1s[(qt * 16 + col) * LS + kt * 32 + quad * 8];
      acc = __builtin_amdgcn_mfma_f32_16x16x32_bf16(a2[kt], bfrag, acc, 0, 0, 0);
    }
    #pragma unroll
    for (int r = 0; r < 4; ++r) {
      float sg = 1.f / (1.f + __expf(-(acc[r] + b2v[r])));
      int addr = (qt * 16 + col) * FS + 64 + cb + quad * 4 + r;
      pxa[addr] = f2bu(us2f(pxa[addr]) * (1.f - sg));
    }
  }
  __syncthreads();
  #pragma unroll
  for (int qt = 0; qt < 4; ++qt) {
    f32x4 acc = {0.f, 0.f, 0.f, 0.f};
    #pragma unroll
    for (int kt = 0; kt < 4; ++kt) {
      short8 bfrag = *(const short8*)&pxa[(qt * 16 + col) * FS + kt * 32 + quad * 8];
      acc = __builtin_amdgcn_mfma_f32_16x16x32_bf16(af[kt], bfrag, acc, 0, 0, 0);
    }
    int qp = qpl[qt * 16 + col];
    if (qp >= 0) {
      #pragma unroll
      for (int r = 0; r < 4; ++r)
        outp[((size_t)b * CC + cb + quad * 4 + r) * NN + qp] = acc[r];
    }
  }
}

// -------- 10a. global max of visatt ----------------------------------------
__global__ __launch_bounds__(256) void k_vmax(const float* __restrict__ vis, unsigned int* __restrict__ vmaxb) {
  int i = blockIdx.x * 256 + threadIdx.x;
  float v = vis[i];
  #pragma unroll
  for (int off = 32; off > 0; off >>= 1) v = fmaxf(v, __shfl_down(v, off));
  if ((threadIdx.x & 63) == 0) atomicMax(vmaxb, __float_as_uint(v));
}

// -------- 10b. x8 nearest upsample + normalize -----------------------------
__global__ __launch_bounds__(256) void k_upsample(const float* __restrict__ vis,
                                                  const unsigned int* __restrict__ vmaxb,
                                                  float* __restrict__ out2) {
  int i = blockIdx.x * 256 + threadIdx.x;
  int b = i >> 18;
  int rem = i & 262143;
  int y = rem >> 9, x = rem & 511;
  float vm = __uint_as_float(vmaxb[0]);
  if (!(vm > 0.f)) vm = 1.f;
  out2[i] = vis[b * NN + (y >> 3) * 64 + (x >> 3)] / vm;
}

extern "C" void kernel_launch(void* const* d_in, const int* in_sizes, int n_in,
                              void* d_out, int out_size, void* d_ws, size_t ws_size,
                              hipStream_t stream) {
  const float* x    = (const float*)d_in[0];
  const float* mask = (const float*)d_in[1];
  const float* w1   = (const float*)d_in[2];
  const float* w2c  = (const float*)d_in[3];
  const float* fsw1 = (const float*)d_in[4];
  const float* fsw2 = (const float*)d_in[5];
  const float* fsb2 = (const float*)d_in[6];
  const float* fswf = (const float*)d_in[7];
  float* out = (float*)d_out;
  char* wsb = (char*)d_ws;

  float* afc = (float*)(wsb + WB_AFC);
  float* den = (float*)(wsb + WB_DEN);
  float* vis = (float*)(wsb + WB_VIS);
  int* qidx  = (int*)(wsb + WB_QIX);
  int* kidx  = (int*)(wsb + WB_KIX);
  unsigned char* mfl = (unsigned char*)(wsb + WB_MFL);
  int* nq = (int*)(wsb + WB_CNT);
  int* nk = nq + 4;
  unsigned int* vmaxb = (unsigned int*)(nq + 8);
  float* gstat = (float*)(wsb + WB_STAT);
  float* gsum1 = gstat;
  float* gsq1  = gstat + 256;
  float* gsum2 = gstat + 512;
  float* gsq2  = gstat + 768;
  unsigned short* wT1 = (unsigned short*)(wsb + WB_WT1);
  unsigned short* wT2 = (unsigned short*)(wsb + WB_WT2);
  unsigned short* wall = (unsigned short*)(wsb + WB_WFB);
  unsigned short* y1t = (unsigned short*)(wsb + WB_AFC);   // 2 MB, dead before k_knorm zeroes afc

  // scratch staged inside d_out:
  unsigned short* kxt = (unsigned short*)out;
  unsigned short* khat = kxt;
  unsigned short* xt = (unsigned short*)(out + 1048576);

  k_maxpool<<<256, 256, 0, stream>>>(mask, mfl, vis, gstat, vmaxb);
  k_compact<<<4, 64, 0, stream>>>(mfl, qidx, kidx, nq, nk);
  k_xT<<<256, 256, 0, stream>>>(x, xt);
  k_wprep<<<224, 256, 0, stream>>>(w1, w2c, fsw1, fsw2, fswf, wT1, wT2, wall);
  k_convm<false><<<dim3(64, BB), 256, 0, stream>>>(xt, wT1, nullptr, nullptr, y1t, gsum1, gsq1);
  k_convm<true><<<dim3(64, BB), 256, 0, stream>>>(y1t, wT2, gsum1, gsq1, kxt, gsum2, gsq2);
  k_knorm<<<256, 256, 0, stream>>>(kxt, xt, gsum2, gsq2, afc, den);
  k_att1<<<dim3(512, BB), 256, 0, stream>>>(khat, xt, qidx, kidx, nq, nk, afc, den);
  k_att2<<<dim3(512, BB), 256, 0, stream>>>(khat, qidx, kidx, nq, nk, den, vis);
  k_copy<<<1024, 256, 0, stream>>>((const uint4*)x, (uint4*)out, 262144);
  k_fusionm<<<dim3(64, BB), 256, 0, stream>>>(xt, afc, den, qidx, nq, wall, fsb2, out);
  k_vmax<<<64, 256, 0, stream>>>(vis, vmaxb);
  k_upsample<<<4096, 256, 0, stream>>>(vis, vmaxb, out + 1048576);
}